// Round 12
// baseline (136.756 us; speedup 1.0000x reference)
//
#include <hip/hip_runtime.h>
#include <hip/hip_bf16.h>

// CausalSelfAttention: B=4 T=2048 H=1024 NH=16 HD=64, fp32 I/O, bf16 MFMA internal.
// cvt_all(X,W*)->bf16 + w=exp2(mask*log2e) ; fused QKV NT-GEMM v3: 128x128x32,
// 4 waves (2x2, wave 64x64, acc 64 VGPR), 32KB LDS dbuf -> 3 RESIDENT BLOCKS/CU
// (TLP covers barrier/vmcnt stalls; R8/R11's 1-block/CU configs both plateaued
// at ~740TF), T2 swizzle slot^=(row&3) on 64B rows, counted vmcnt(4), grid 1536
// (8x192 XCD-bijective, which=bid%3), LDS-staged coalesced epilogue ;
// flash attn: q-tile PAIR blocks (structural balance), QBLK=128, triple-buffered
// K/V prefetch depth 2, swapped QK^T, no-max exp2 softmax, w-fragment denominator.

typedef float  f32x4 __attribute__((ext_vector_type(4)));
typedef short  s16x8 __attribute__((ext_vector_type(8)));
typedef unsigned short u16;

#define LOG2E 1.44269504088896340736f

__device__ __forceinline__ u16 f2bf(float f) {
  unsigned u = __float_as_uint(f);
  u += 0x7FFFu + ((u >> 16) & 1u);   // RNE (inputs finite)
  return (u16)(u >> 16);
}
__device__ __forceinline__ float bf2f(u16 v) {
  return __uint_as_float(((unsigned)v) << 16);
}
__device__ __forceinline__ float ex2(float x) {
#if __has_builtin(__builtin_amdgcn_exp2f)
  return __builtin_amdgcn_exp2f(x);
#else
  return exp2f(x);
#endif
}
__device__ __forceinline__ float rcp_(float x) {
#if __has_builtin(__builtin_amdgcn_rcpf)
  return __builtin_amdgcn_rcpf(x);
#else
  return 1.0f / x;
#endif
}
__device__ __forceinline__ unsigned cvtpk(float lo, float hi) {
  unsigned r;
  asm("v_cvt_pk_bf16_f32 %0, %1, %2" : "=v"(r) : "v"(lo), "v"(hi));
  return r;
}
__device__ __forceinline__ void bar() {
  asm volatile("" ::: "memory");
  __builtin_amdgcn_s_barrier();
  asm volatile("" ::: "memory");
}

#define GLOAD16(gp, lp)                                                          \
  __builtin_amdgcn_global_load_lds(                                              \
      (const __attribute__((address_space(1))) void*)(gp),                       \
      (__attribute__((address_space(3))) void*)(lp), 16, 0, 0)

#define MFMA(a, b, c) __builtin_amdgcn_mfma_f32_16x16x32_bf16((a), (b), (c), 0, 0, 0)

// ---------------------------- fp32 -> bf16 (X, Wq, Wk, Wv) + w = exp2(mask*log2e)
__global__ __launch_bounds__(256) void cvt_all(
    const float* __restrict__ hs, const float* __restrict__ wq,
    const float* __restrict__ wk, const float* __restrict__ wv,
    const float* __restrict__ maskp,
    u16* __restrict__ xo, u16* __restrict__ qo, u16* __restrict__ ko,
    u16* __restrict__ vo, u16* __restrict__ wm) {
  int b = blockIdx.x;
  const float* s;
  u16* d;
  size_t i;
  bool isw = false;
  if (b < 4096) { s = hs; d = xo; i = (size_t)b * 256 + threadIdx.x; }
  else if (b < 5632) {
    int w = (b - 4096) >> 9, r = (b - 4096) & 511;
    s = (w == 0) ? wq : (w == 1) ? wk : wv;
    d = (w == 0) ? qo : (w == 1) ? ko : vo;
    i = (size_t)r * 256 + threadIdx.x;
  } else {  // 4 blocks: w = exp2(mask * log2e), 8192 elems
    s = maskp; d = wm; i = (size_t)(b - 5632) * 256 + threadIdx.x;
    isw = true;
  }
  const float4* sp = (const float4*)s + i * 2;
  float4 a = sp[0], c = sp[1];
  s16x8 r8;
  if (isw) {
    r8[0] = f2bf(ex2(a.x * LOG2E)); r8[1] = f2bf(ex2(a.y * LOG2E));
    r8[2] = f2bf(ex2(a.z * LOG2E)); r8[3] = f2bf(ex2(a.w * LOG2E));
    r8[4] = f2bf(ex2(c.x * LOG2E)); r8[5] = f2bf(ex2(c.y * LOG2E));
    r8[6] = f2bf(ex2(c.z * LOG2E)); r8[7] = f2bf(ex2(c.w * LOG2E));
  } else {
    r8[0] = f2bf(a.x); r8[1] = f2bf(a.y); r8[2] = f2bf(a.z); r8[3] = f2bf(a.w);
    r8[4] = f2bf(c.x); r8[5] = f2bf(c.y); r8[6] = f2bf(c.z); r8[7] = f2bf(c.w);
  }
  *(s16x8*)(d + i * 8) = r8;
}

// ------------------------------------------------------------------- QKV GEMM
// 128x128 tile, BK=32, 4 waves (2x2, wave 64x64, acc[4][4]=64 VGPR).
// LDS 32KB: A dbuf 2x8KB @0, B dbuf 2x8KB @16384 -> 3 blocks/CU resident.
// 64B rows, involution swizzle slot^=(row&3) on staging SOURCE + frag reads.
// Per K-tile: STAGE(next, 4 gloads); vmcnt(4); bar; 8 ds_read + 16 MFMA; bar.
__global__ __launch_bounds__(256, 3) void qkv_gemm(
    const u16* __restrict__ Xb,
    const u16* __restrict__ Wqb, const u16* __restrict__ Wkb,
    const u16* __restrict__ Wvb,
    const float* __restrict__ bq, const float* __restrict__ bk,
    const float* __restrict__ bv, const u16* __restrict__ Wm,
    u16* __restrict__ Qo, u16* __restrict__ Ko, u16* __restrict__ Vto) {
  int bid0 = blockIdx.x;
  int bid  = (bid0 & 7) * 192 + (bid0 >> 3);  // XCD swizzle, 1536 = 8*192
  int which = bid % 3;                        // balanced Q/K/V mix per XCD
  int rt = bid / 3;                           // 0..511
  int mt = rt >> 3, ntl = rt & 7;             // 64 m-tiles x 8 n-tiles
  const u16* W = (which == 0) ? Wqb : (which == 1) ? Wkb : Wvb;
  const float* bias = (which == 0) ? bq : (which == 1) ? bk : bv;

  __shared__ __align__(16) char lds[32768];

  int tid = threadIdx.x;
  int lane = tid & 63, wid = tid >> 6;
  int q16 = lane & 15, g = lane >> 4;
  int wr = wid >> 1, wc = wid & 1;            // 2M x 2N

  // staging source (pre-swizzled): thread covers (row = tid>>2 [+64], slot tid&3)
  int srow = tid >> 2;
  int ssw = ((tid & 3) ^ (srow & 3)) << 4;    // byte offset within 64B row
  const char* Asrc = (const char*)Xb + (size_t)(mt * 128 + srow) * 2048 + ssw;
  const char* Bsrc = (const char*)W  + (size_t)(ntl * 128 + srow) * 2048 + ssw;

  int slotA = (g ^ (q16 & 3)) << 4;           // frag-read slot (row&3 == q16&3)

#define STAGE(i, buf) do { size_t co = (size_t)(i) * 64;                         \
    GLOAD16(Asrc + co,          lds + (buf) * 8192 + tid * 16);                  \
    GLOAD16(Asrc + co + 131072, lds + (buf) * 8192 + 4096 + tid * 16);           \
    GLOAD16(Bsrc + co,          lds + 16384 + (buf) * 8192 + tid * 16);          \
    GLOAD16(Bsrc + co + 131072, lds + 16384 + (buf) * 8192 + 4096 + tid * 16); } while (0)

  STAGE(0, 0);

  f32x4 acc[4][4] = {};
  s16x8 af[4], bf[4];

#pragma unroll 1
  for (int i = 0; i < 32; ++i) {
    int buf = i & 1;
    if (i < 31) {
      STAGE(i + 1, buf ^ 1);
      asm volatile("s_waitcnt vmcnt(4)" ::: "memory");  // tile i's 4 loads done
    } else {
      asm volatile("s_waitcnt vmcnt(0)" ::: "memory");
    }
    bar();
    const char* pa = lds + buf * 8192 + (wr * 64 + q16) * 64 + slotA;
    const char* pb = lds + 16384 + buf * 8192 + (wc * 64 + q16) * 64 + slotA;
#pragma unroll
    for (int m = 0; m < 4; ++m) af[m] = *(const s16x8*)(pa + m * 1024);
#pragma unroll
    for (int n = 0; n < 4; ++n) bf[n] = *(const s16x8*)(pb + n * 1024);
    __builtin_amdgcn_s_setprio(1);
#pragma unroll
    for (int m = 0; m < 4; ++m)
#pragma unroll
      for (int n = 0; n < 4; ++n)
        acc[m][n] = MFMA(af[m], bf[n], acc[m][n]);
    __builtin_amdgcn_s_setprio(0);
    bar();  // all reads of buf done before iter i+1 STAGEs into it
  }
#undef STAGE

  // ---- epilogue: per-wave 8KB LDS region, 2 passes of 32 rows, coalesced ----
  float qsc = (which == 0) ? (0.125f * LOG2E) : 1.0f;
  u16* Out = (which == 0) ? Qo : (which == 1) ? Ko : Vto;
  int h0 = ntl * 2 + wc;                      // wave's head
  int m_base = mt * 128 + wr * 64;
  int bb = m_base >> 11, t0 = m_base & 2047;
  u16* tile = (u16*)(void*)(lds + wid * 8192);  // [32][72] u16 per pass
  const char* tb = (const char*)tile;
  int rl = lane >> 3, cb = (lane & 7) * 16;

  float wv[4][4];
  if (which == 2) {
    const u16* wrow = Wm + (size_t)bb * 2048 + t0;
#pragma unroll
    for (int m = 0; m < 4; ++m)
#pragma unroll
      for (int j = 0; j < 4; ++j)
        wv[m][j] = bf2f(wrow[m * 16 + g * 4 + j]);
  }

#define EPIPASS(P) do {                                                          \
    if (which != 2) {                                                            \
      _Pragma("unroll")                                                          \
      for (int ml = 0; ml < 2; ++ml) {                                           \
        _Pragma("unroll")                                                        \
        for (int n = 0; n < 4; ++n) {                                            \
          float bvl = bias[h0 * 64 + n * 16 + q16];                              \
          _Pragma("unroll")                                                      \
          for (int j = 0; j < 4; ++j)                                            \
            tile[(ml * 16 + g * 4 + j) * 72 + n * 16 + q16] =                    \
                f2bf((acc[2 * (P) + ml][n][j] + bvl) * qsc);                     \
        }                                                                        \
      }                                                                          \
    } else {                                                                     \
      _Pragma("unroll")                                                          \
      for (int nl = 0; nl < 2; ++nl) {                                           \
        float bvl = bias[h0 * 64 + (2 * (P) + nl) * 16 + q16];                   \
        _Pragma("unroll")                                                        \
        for (int m = 0; m < 4; ++m)                                              \
          _Pragma("unroll")                                                      \
          for (int j = 0; j < 4; ++j)                                            \
            tile[(nl * 16 + q16) * 72 + m * 16 + g * 4 + j] =                    \
                f2bf((acc[m][2 * (P) + nl][j] + bvl) * wv[m][j]);                \
      }                                                                          \
    }                                                                            \
    asm volatile("" ::: "memory");                                               \
    if (which != 2) {                                                            \
      char* gb = (char*)(Out + ((size_t)(bb * 16 + h0) * 2048 + t0) * 64);       \
      _Pragma("unroll")                                                          \
      for (int c = 0; c < 4; ++c) {                                              \
        int row = rl + c * 8;                                                    \
        s16x8 v = *(const s16x8*)(tb + row * 144 + cb);                          \
        *(s16x8*)(gb + (size_t)(32 * (P) + row) * 128 + cb) = v;                 \
      }                                                                          \
    } else {                                                                     \
      char* gb = (char*)Out + ((size_t)(bb * 16 + h0) * 64 + 32 * (P)) * 4096 +  \
                 t0 * 2;                                                         \
      _Pragma("unroll")                                                          \
      for (int c = 0; c < 4; ++c) {                                              \
        int row = rl + c * 8;                                                    \
        s16x8 v = *(const s16x8*)(tb + row * 144 + cb);                          \
        *(s16x8*)(gb + (size_t)row * 4096 + cb) = v;                             \
      }                                                                          \
    }                                                                            \
    asm volatile("" ::: "memory"); } while (0)

  EPIPASS(0);
  EPIPASS(1);
#undef EPIPASS
}

// ------------------------------------------------------------- flash attention
// grid 512 = 64 bh x 8 pair-blocks. Block p processes q-tiles (15-p) then (p)
// of bh -> exactly 34 k-tiles per block. 4 waves x 32 q-rows (2 halves).
// Triple-buffered K/V, prefetch depth 2, counted vmcnt(8)/(4)/(0).
__global__ __launch_bounds__(256, 2) void attn_fwd(
    const u16* __restrict__ Qw, const u16* __restrict__ Kw,
    const u16* __restrict__ Vtw, const u16* __restrict__ Wm,
    float* __restrict__ out) {
  int bid0 = blockIdx.x;
  int bid = (bid0 & 7) * 64 + (bid0 >> 3);  // XCD swizzle: 8 bh per XCD
  int bh = bid >> 3, p = bid & 7;
  int tid = threadIdx.x;
  int lane = tid & 63, wid = tid >> 6;
  int q16 = lane & 15, g = lane >> 4;

  __shared__ __align__(16) char Ks[3][8192];   // [k 64][128B] swizzled
  __shared__ __align__(16) char Vs[3][8192];   // V^T [d 64][128B k] swizzled
  __shared__ __align__(16) u16 wl[2048];       // w row (bf16)

  int srow = tid >> 3;
  int sinner = (tid & 7) << 4;
  int fs = (srow & 7) ^ ((srow >> 1) & 4);
  int ssw = sinner ^ (fs << 4);
  const char* Kg = (const char*)Kw + ((size_t)bh * 2048 + srow) * 128 + ssw;
  const char* Vg = (const char*)Vtw + ((size_t)bh * 64 + srow) * 4096 + ssw;

#define STAGE_T(kt, b) do {                                                      \
    GLOAD16(Kg + (size_t)(kt) * 8192,        Ks[b] + tid * 16);                  \
    GLOAD16(Kg + (size_t)(kt) * 8192 + 4096, Ks[b] + tid * 16 + 4096);           \
    GLOAD16(Vg + (size_t)(kt) * 128,          Vs[b] + tid * 16);                 \
    GLOAD16(Vg + (size_t)(kt) * 128 + 131072, Vs[b] + tid * 16 + 4096); } while (0)

  // wl staged once (retired by first vmcnt(8); visible after first barrier)
  GLOAD16((const char*)Wm + (size_t)(bh >> 4) * 4096 + tid * 16,
          (char*)wl + tid * 16);

  auto run_phase = [&](int qtl) {
    int nt = 2 * qtl + 2;
    int qw0 = (qtl << 7) + wid * 32;
    size_t qr = (size_t)bh * 2048 + qw0 + q16;
    s16x8 qa[2][2];
#pragma unroll
    for (int h = 0; h < 2; ++h) {
      qa[h][0] = *(const s16x8*)(Qw + (qr + 16 * h) * 64 + g * 8);
      qa[h][1] = *(const s16x8*)(Qw + (qr + 16 * h) * 64 + 32 + g * 8);
    }
    STAGE_T(0, 0);
    STAGE_T(1, 1);

    f32x4 o[2][4] = {};
    f32x4 lw[2] = {};
    int bc = 0;  // kt % 3

#pragma unroll 1
    for (int kt = 0; kt < nt; ++kt) {
      if (kt + 2 < nt) {
        int bp = bc + 2; if (bp >= 3) bp -= 3;
        STAGE_T(kt + 2, bp);
        asm volatile("s_waitcnt vmcnt(8)" ::: "memory");
      } else if (kt + 1 < nt) {
        asm volatile("s_waitcnt vmcnt(4)" ::: "memory");
      } else {
        asm volatile("s_waitcnt vmcnt(0)" ::: "memory");
      }
      __builtin_amdgcn_s_barrier();
      asm volatile("" ::: "memory");

      if (64 * kt <= qw0 + 31) {
        int kb = kt << 6;
        const char* ksb = Ks[bc];
        const char* vsb = Vs[bc];
        bool causal = (64 * kt + 63 > qw0);
#pragma unroll
        for (int c = 0; c < 2; ++c) {
          f32x4 sA[2][2];
          __builtin_amdgcn_s_setprio(1);
#pragma unroll
          for (int t4 = 0; t4 < 2; ++t4) {
            int kk = 32 * c + ((q16 >> 2) << 3) + (t4 << 2) + (q16 & 3);
            int fk = (kk & 7) ^ ((kk >> 1) & 4);
            const char* krow = ksb + kk * 128;
            int in0 = (g * 16) ^ (fk << 4);
            s16x8 kf0 = *(const s16x8*)(krow + in0);
            s16x8 kf1 = *(const s16x8*)(krow + (in0 ^ 64));
#pragma unroll
            for (int h = 0; h < 2; ++h) {
              f32x4 sv = {0.f, 0.f, 0.f, 0.f};
              sv = MFMA(kf0, qa[h][0], sv);
              sv = MFMA(kf1, qa[h][1], sv);
              sA[t4][h] = sv;
            }
          }
          __builtin_amdgcn_s_setprio(0);

          s16x8 wf = *(const s16x8*)((const char*)wl + (kb + 32 * c + 8 * g) * 2);

          union { s16x8 v; unsigned u[4]; } pb[2];
#pragma unroll
          for (int h = 0; h < 2; ++h) {
            int qc = qw0 + 16 * h + q16;
#pragma unroll
            for (int t4 = 0; t4 < 2; ++t4) {
              float a0 = ex2(sA[t4][h][0]), a1 = ex2(sA[t4][h][1]);
              float a2 = ex2(sA[t4][h][2]), a3 = ex2(sA[t4][h][3]);
              if (causal) {
                int k0 = kb + 32 * c + 8 * g + 4 * t4;
                a0 = (k0 + 0 <= qc) ? a0 : 0.f;
                a1 = (k0 + 1 <= qc) ? a1 : 0.f;
                a2 = (k0 + 2 <= qc) ? a2 : 0.f;
                a3 = (k0 + 3 <= qc) ? a3 : 0.f;
              }
              pb[h].u[t4 * 2 + 0] = cvtpk(a0, a1);
              pb[h].u[t4 * 2 + 1] = cvtpk(a2, a3);
            }
          }

          __builtin_amdgcn_s_setprio(1);
#pragma unroll
          for (int dt = 0; dt < 4; ++dt) {
            int d = dt * 16 + q16;
            int fv = (d & 7) ^ ((d >> 1) & 4);
            s16x8 vf = *(const s16x8*)(vsb + d * 128 + ((64 * c + 16 * g) ^ (fv << 4)));
#pragma unroll
            for (int h = 0; h < 2; ++h)
              o[h][dt] = MFMA(vf, pb[h].v, o[h][dt]);
          }
#pragma unroll
          for (int h = 0; h < 2; ++h)
            lw[h] = MFMA(wf, pb[h].v, lw[h]);
          __builtin_amdgcn_s_setprio(0);
        }
      }
      __builtin_amdgcn_s_barrier();
      asm volatile("" ::: "memory");
      if (++bc >= 3) bc -= 3;
    }

#pragma unroll
    for (int h = 0; h < 2; ++h) {
      float inv = rcp_(lw[h][0]);
      float* op = out + ((size_t)bh * 2048 + qw0 + 16 * h + q16) * 64 + g * 4;
#pragma unroll
      for (int dt = 0; dt < 4; ++dt)
        *(f32x4*)(op + dt * 16) = o[h][dt] * inv;
    }
  };

  run_phase(15 - p);   // heavy tile: 32-2p k-tiles
  run_phase(p);        // light tile: 2p+2 k-tiles (total 34, constant)
#undef STAGE_T
}

// ------------------------------------------------------------------- launcher
extern "C" void kernel_launch(void* const* d_in, const int* in_sizes, int n_in,
                              void* d_out, int out_size, void* d_ws, size_t ws_size,
                              hipStream_t stream) {
  const float* hs   = (const float*)d_in[0];
  const float* mask = (const float*)d_in[1];
  const float* Wq   = (const float*)d_in[2];
  const float* bq   = (const float*)d_in[3];
  const float* Wk   = (const float*)d_in[4];
  const float* bk   = (const float*)d_in[5];
  const float* Wv   = (const float*)d_in[6];
  const float* bv   = (const float*)d_in[7];
  float* out = (float*)d_out;

  char* w = (char*)d_ws;
  u16* Xb  = (u16*)w; w += (size_t)8192 * 1024 * 2;
  u16* Wqb = (u16*)w; w += (size_t)1024 * 1024 * 2;
  u16* Wkb = (u16*)w; w += (size_t)1024 * 1024 * 2;
  u16* Wvb = (u16*)w; w += (size_t)1024 * 1024 * 2;
  u16* Qw  = (u16*)w; w += (size_t)8192 * 1024 * 2;
  u16* Kw  = (u16*)w; w += (size_t)8192 * 1024 * 2;
  u16* Vtw = (u16*)w; w += (size_t)8192 * 1024 * 2;
  u16* Wm  = (u16*)w; w += (size_t)8192 * 2;

  cvt_all<<<5636, 256, 0, stream>>>(hs, Wq, Wk, Wv, mask, Xb, Wqb, Wkb, Wvb, Wm);
  qkv_gemm<<<1536, 256, 0, stream>>>(Xb, Wqb, Wkb, Wvb, bq, bk, bv, Wm, Qw, Kw, Vtw);
  attn_fwd<<<512, 256, 0, stream>>>(Qw, Kw, Vtw, Wm, out);
}

// Round 14
// 130.306 us; speedup vs baseline: 1.0495x; 1.0495x over previous
//
#include <hip/hip_runtime.h>
#include <hip/hip_bf16.h>

// CausalSelfAttention: B=4 T=2048 H=1024 NH=16 HD=64, fp32 I/O, bf16 MFMA internal.
// cvt_all(X,W*)->bf16 + w=exp2(mask*log2e) ; fused QKV NT-GEMM (R8's measured-best:
// 256x128x64, 2-barrier counted-vmcnt(6), T2 swizzle, which=bid%3, LDS-staged
// coalesced epilogue, V rows pre-scaled by w) ; flash attn v6b: q-tile PAIR blocks,
// QBLK=128, QUAD-buffered K/V with prefetch depth 2 (SAFE: STAGE(kt+2) writes buf
// (kt-2)&3 whose readers provably finished before bar(kt-1); depth 3 raced — R13),
// ONE barrier per k-tile, counted vmcnt(8)/(4)/(0), swapped QK^T, no-max exp2
// softmax, w-fragment denominator, P in registers.

typedef float  f32x4 __attribute__((ext_vector_type(4)));
typedef short  s16x8 __attribute__((ext_vector_type(8)));
typedef unsigned short u16;

#define LOG2E 1.44269504088896340736f

__device__ __forceinline__ u16 f2bf(float f) {
  unsigned u = __float_as_uint(f);
  u += 0x7FFFu + ((u >> 16) & 1u);   // RNE (inputs finite)
  return (u16)(u >> 16);
}
__device__ __forceinline__ float bf2f(u16 v) {
  return __uint_as_float(((unsigned)v) << 16);
}
__device__ __forceinline__ float ex2(float x) {
#if __has_builtin(__builtin_amdgcn_exp2f)
  return __builtin_amdgcn_exp2f(x);
#else
  return exp2f(x);
#endif
}
__device__ __forceinline__ float rcp_(float x) {
#if __has_builtin(__builtin_amdgcn_rcpf)
  return __builtin_amdgcn_rcpf(x);
#else
  return 1.0f / x;
#endif
}
__device__ __forceinline__ unsigned cvtpk(float lo, float hi) {
  unsigned r;
  asm("v_cvt_pk_bf16_f32 %0, %1, %2" : "=v"(r) : "v"(lo), "v"(hi));
  return r;
}
__device__ __forceinline__ void bar() {
  asm volatile("" ::: "memory");
  __builtin_amdgcn_s_barrier();
  asm volatile("" ::: "memory");
}

#define GLOAD16(gp, lp)                                                          \
  __builtin_amdgcn_global_load_lds(                                              \
      (const __attribute__((address_space(1))) void*)(gp),                       \
      (__attribute__((address_space(3))) void*)(lp), 16, 0, 0)

#define MFMA(a, b, c) __builtin_amdgcn_mfma_f32_16x16x32_bf16((a), (b), (c), 0, 0, 0)

// ---------------------------- fp32 -> bf16 (X, Wq, Wk, Wv) + w = exp2(mask*log2e)
__global__ __launch_bounds__(256) void cvt_all(
    const float* __restrict__ hs, const float* __restrict__ wq,
    const float* __restrict__ wk, const float* __restrict__ wv,
    const float* __restrict__ maskp,
    u16* __restrict__ xo, u16* __restrict__ qo, u16* __restrict__ ko,
    u16* __restrict__ vo, u16* __restrict__ wm) {
  int b = blockIdx.x;
  const float* s;
  u16* d;
  size_t i;
  bool isw = false;
  if (b < 4096) { s = hs; d = xo; i = (size_t)b * 256 + threadIdx.x; }
  else if (b < 5632) {
    int w = (b - 4096) >> 9, r = (b - 4096) & 511;
    s = (w == 0) ? wq : (w == 1) ? wk : wv;
    d = (w == 0) ? qo : (w == 1) ? ko : vo;
    i = (size_t)r * 256 + threadIdx.x;
  } else {  // 4 blocks: w = exp2(mask * log2e), 8192 elems
    s = maskp; d = wm; i = (size_t)(b - 5632) * 256 + threadIdx.x;
    isw = true;
  }
  const float4* sp = (const float4*)s + i * 2;
  float4 a = sp[0], c = sp[1];
  s16x8 r8;
  if (isw) {
    r8[0] = f2bf(ex2(a.x * LOG2E)); r8[1] = f2bf(ex2(a.y * LOG2E));
    r8[2] = f2bf(ex2(a.z * LOG2E)); r8[3] = f2bf(ex2(a.w * LOG2E));
    r8[4] = f2bf(ex2(c.x * LOG2E)); r8[5] = f2bf(ex2(c.y * LOG2E));
    r8[6] = f2bf(ex2(c.z * LOG2E)); r8[7] = f2bf(ex2(c.w * LOG2E));
  } else {
    r8[0] = f2bf(a.x); r8[1] = f2bf(a.y); r8[2] = f2bf(a.z); r8[3] = f2bf(a.w);
    r8[4] = f2bf(c.x); r8[5] = f2bf(c.y); r8[6] = f2bf(c.z); r8[7] = f2bf(c.w);
  }
  *(s16x8*)(d + i * 8) = r8;
}

// ------------------------------------------------------------------- QKV GEMM
// R8's measured-best (67.4us): 256x128 tile, BK=64, 8 waves (4m x 2n, 64x64).
// LDS 96KB dbuf; T2 involution swizzle slot^=(row&7); per K-tile:
// STAGE(next); vmcnt(6); bar; ds_read+MFMA; bar. LDS-staged coalesced epilogue.
__global__ __launch_bounds__(512, 2) void qkv_gemm(
    const u16* __restrict__ Xb,
    const u16* __restrict__ Wqb, const u16* __restrict__ Wkb,
    const u16* __restrict__ Wvb,
    const float* __restrict__ bq, const float* __restrict__ bk,
    const float* __restrict__ bv, const u16* __restrict__ Wm,
    u16* __restrict__ Qo, u16* __restrict__ Ko, u16* __restrict__ Vto) {
  int bid0 = blockIdx.x;
  int bid  = (bid0 & 7) * 96 + (bid0 >> 3);
  int which = bid % 3;
  int rt = bid / 3;
  int mt = rt >> 3, nt = rt & 7;
  const u16* W = (which == 0) ? Wqb : (which == 1) ? Wkb : Wvb;
  const float* bias = (which == 0) ? bq : (which == 1) ? bk : bv;

  __shared__ __align__(16) char lds[98304];

  int tid = threadIdx.x;
  int lane = tid & 63, wid = tid >> 6;
  int q16 = lane & 15, g = lane >> 4;
  int wr = wid >> 1, wc = wid & 1;

  int srow = tid >> 3, sslot = tid & 7;
  int sw = (sslot ^ (srow & 7)) << 4;
  const char* Asrc = (const char*)Xb + (size_t)(mt * 256 + srow) * 2048 + sw;
  const char* Bsrc = (const char*)W  + (size_t)(nt * 128 + srow) * 2048 + sw;

  int slot0 = (g ^ (q16 & 7)) << 4;

#define STAGE_AB(tt, buf) do { size_t so = (size_t)(tt) * 128;                   \
    GLOAD16(Asrc + so,          lds + (buf) * 32768 + tid * 16);                 \
    GLOAD16(Asrc + so + 131072, lds + (buf) * 32768 + 8192 + tid * 16);          \
    GLOAD16(Asrc + so + 262144, lds + (buf) * 32768 + 16384 + tid * 16);         \
    GLOAD16(Asrc + so + 393216, lds + (buf) * 32768 + 24576 + tid * 16);         \
    GLOAD16(Bsrc + so,          lds + 65536 + (buf) * 16384 + tid * 16);         \
    GLOAD16(Bsrc + so + 131072, lds + 65536 + (buf) * 16384 + 8192 + tid * 16); } while (0)

#define LDA(FA, buf, mp) do {                                                    \
    const char* p_ = lds + (buf) * 32768 + (wr * 64 + (mp) * 32 + q16) * 128;    \
    FA[0] = *(const s16x8*)(p_ + slot0);                                         \
    FA[1] = *(const s16x8*)(p_ + (slot0 ^ 64));                                  \
    FA[2] = *(const s16x8*)(p_ + 2048 + slot0);                                  \
    FA[3] = *(const s16x8*)(p_ + 2048 + (slot0 ^ 64)); } while (0)

#define LDB(FB, buf) do {                                                        \
    const char* p_ = lds + 65536 + (buf) * 16384 + (wc * 64 + q16) * 128;        \
    FB[0] = *(const s16x8*)(p_ + slot0);                                         \
    FB[1] = *(const s16x8*)(p_ + (slot0 ^ 64));                                  \
    FB[2] = *(const s16x8*)(p_ + 2048 + slot0);                                  \
    FB[3] = *(const s16x8*)(p_ + 2048 + (slot0 ^ 64));                           \
    FB[4] = *(const s16x8*)(p_ + 4096 + slot0);                                  \
    FB[5] = *(const s16x8*)(p_ + 4096 + (slot0 ^ 64));                           \
    FB[6] = *(const s16x8*)(p_ + 6144 + slot0);                                  \
    FB[7] = *(const s16x8*)(p_ + 6144 + (slot0 ^ 64)); } while (0)

#define MM16(mlo, FA, FB) do {                                                   \
    _Pragma("unroll")                                                            \
    for (int n_ = 0; n_ < 4; ++n_) {                                             \
      acc[(mlo)][n_]     = MFMA(FA[0], FB[2 * n_],     acc[(mlo)][n_]);          \
      acc[(mlo)][n_]     = MFMA(FA[1], FB[2 * n_ + 1], acc[(mlo)][n_]);          \
      acc[(mlo) + 1][n_] = MFMA(FA[2], FB[2 * n_],     acc[(mlo) + 1][n_]);      \
      acc[(mlo) + 1][n_] = MFMA(FA[3], FB[2 * n_ + 1], acc[(mlo) + 1][n_]);      \
    } } while (0)

  STAGE_AB(0, 0);

  f32x4 acc[4][4] = {};
  s16x8 fA0[4], fA1[4], fB[8];

#pragma unroll 1
  for (int i = 0; i < 16; ++i) {
    int buf = i & 1;
    if (i < 15) {
      STAGE_AB(i + 1, buf ^ 1);
      asm volatile("s_waitcnt vmcnt(6)" ::: "memory");
    } else {
      asm volatile("s_waitcnt vmcnt(0)" ::: "memory");
    }
    bar();
    LDA(fA0, buf, 0);
    LDA(fA1, buf, 1);
    LDB(fB, buf);
    __builtin_amdgcn_s_setprio(1);
    MM16(0, fA0, fB);
    MM16(2, fA1, fB);
    __builtin_amdgcn_s_setprio(0);
    bar();
  }

  u16* tile = (u16*)(void*)lds + (size_t)wid * 64 * 72;
  int h0 = nt * 2 + wc;
  int m_base = mt * 256 + wr * 64;
  int bb = m_base >> 11;
  int t0 = m_base & 2047;

  if (which != 2) {
    float qsc = (which == 0) ? (0.125f * LOG2E) : 1.0f;
#pragma unroll
    for (int n = 0; n < 4; ++n) {
      float bvl = bias[h0 * 64 + n * 16 + q16];
#pragma unroll
      for (int m = 0; m < 4; ++m)
#pragma unroll
        for (int j = 0; j < 4; ++j)
          tile[(m * 16 + g * 4 + j) * 72 + n * 16 + q16] =
              f2bf((acc[m][n][j] + bvl) * qsc);
    }
  } else {
    const u16* wrow = Wm + (size_t)bb * 2048 + t0;
    float wv[4][4];
#pragma unroll
    for (int m = 0; m < 4; ++m)
#pragma unroll
      for (int j = 0; j < 4; ++j)
        wv[m][j] = bf2f(wrow[m * 16 + g * 4 + j]);
#pragma unroll
    for (int n = 0; n < 4; ++n) {
      float bvl = bias[h0 * 64 + n * 16 + q16];
#pragma unroll
      for (int m = 0; m < 4; ++m)
#pragma unroll
        for (int j = 0; j < 4; ++j)
          tile[(n * 16 + q16) * 72 + m * 16 + g * 4 + j] =
              f2bf((acc[m][n][j] + bvl) * wv[m][j]);
    }
  }
  asm volatile("" ::: "memory");

  const char* tb = (const char*)tile;
  int rl = lane >> 3, cb = (lane & 7) * 16;
  if (which != 2) {
    u16* Out = (which == 0) ? Qo : Ko;
    char* gbase = (char*)(Out + ((size_t)(bb * 16 + h0) * 2048 + t0) * 64);
#pragma unroll
    for (int c = 0; c < 8; ++c) {
      int row = rl + c * 8;
      s16x8 v = *(const s16x8*)(tb + row * 144 + cb);
      *(s16x8*)(gbase + row * 128 + cb) = v;
    }
  } else {
    char* gbase = (char*)Vto + ((size_t)(bb * 16 + h0) * 64) * 4096 + t0 * 2;
#pragma unroll
    for (int c = 0; c < 8; ++c) {
      int d = rl + c * 8;
      s16x8 v = *(const s16x8*)(tb + d * 144 + cb);
      *(s16x8*)(gbase + (size_t)d * 4096 + cb) = v;
    }
  }
#undef STAGE_AB
#undef LDA
#undef LDB
#undef MM16
}

// ------------------------------------------------------------- flash attention
// grid 512 = 64 bh x 8 pair-blocks (q-tiles 15-p then p -> 34 k-tiles each).
// 4 waves x 32 q-rows. QUAD-buffered K/V, prefetch depth 2 (safe write-to-read
// distance under 1-barrier-per-tile sync), counted vmcnt(8)/(4)/(0).
__global__ __launch_bounds__(256, 2) void attn_fwd(
    const u16* __restrict__ Qw, const u16* __restrict__ Kw,
    const u16* __restrict__ Vtw, const u16* __restrict__ Wm,
    float* __restrict__ out) {
  int bid0 = blockIdx.x;
  int bid = (bid0 & 7) * 64 + (bid0 >> 3);  // XCD swizzle: 8 bh per XCD
  int bh = bid >> 3, p = bid & 7;
  int tid = threadIdx.x;
  int lane = tid & 63, wid = tid >> 6;
  int q16 = lane & 15, g = lane >> 4;

  __shared__ __align__(16) char Ks[4][8192];   // [k 64][128B] swizzled
  __shared__ __align__(16) char Vs[4][8192];   // V^T [d 64][128B k] swizzled
  __shared__ __align__(16) u16 wl[2048];       // w row (bf16)

  int srow = tid >> 3;
  int sinner = (tid & 7) << 4;
  int fs = (srow & 7) ^ ((srow >> 1) & 4);
  int ssw = sinner ^ (fs << 4);
  const char* Kg = (const char*)Kw + ((size_t)bh * 2048 + srow) * 128 + ssw;
  const char* Vg = (const char*)Vtw + ((size_t)bh * 64 + srow) * 4096 + ssw;

#define STAGE_T(kt, b) do {                                                      \
    GLOAD16(Kg + (size_t)(kt) * 8192,        Ks[b] + tid * 16);                  \
    GLOAD16(Kg + (size_t)(kt) * 8192 + 4096, Ks[b] + tid * 16 + 4096);           \
    GLOAD16(Vg + (size_t)(kt) * 128,          Vs[b] + tid * 16);                 \
    GLOAD16(Vg + (size_t)(kt) * 128 + 131072, Vs[b] + tid * 16 + 4096); } while (0)

  // wl staged once (drains as oldest entry at the first counted vmcnt)
  GLOAD16((const char*)Wm + (size_t)(bh >> 4) * 4096 + tid * 16,
          (char*)wl + tid * 16);

  auto run_phase = [&](int qtl) {
    int nt = 2 * qtl + 2;
    int qw0 = (qtl << 7) + wid * 32;
    size_t qr = (size_t)bh * 2048 + qw0 + q16;
    s16x8 qa[2][2];
#pragma unroll
    for (int h = 0; h < 2; ++h) {
      qa[h][0] = *(const s16x8*)(Qw + (qr + 16 * h) * 64 + g * 8);
      qa[h][1] = *(const s16x8*)(Qw + (qr + 16 * h) * 64 + 32 + g * 8);
    }
    bar();              // previous phase's readers done before re-staging bufs
    STAGE_T(0, 0);
    STAGE_T(1, 1);

    f32x4 o[2][4] = {};
    f32x4 lw[2] = {};

#pragma unroll 1
    for (int kt = 0; kt < nt; ++kt) {
      if (kt + 2 < nt) {
        STAGE_T(kt + 2, (kt + 2) & 3);
        asm volatile("s_waitcnt vmcnt(8)" ::: "memory");  // tile kt landed
      } else if (kt + 1 < nt) {
        asm volatile("s_waitcnt vmcnt(4)" ::: "memory");
      } else {
        asm volatile("s_waitcnt vmcnt(0)" ::: "memory");
      }
      bar();            // the ONLY barrier per k-tile

      if (64 * kt <= qw0 + 31) {
        int kb = kt << 6;
        const char* ksb = Ks[kt & 3];
        const char* vsb = Vs[kt & 3];
        bool causal = (64 * kt + 63 > qw0);
#pragma unroll
        for (int c = 0; c < 2; ++c) {
          f32x4 sA[2][2];
          __builtin_amdgcn_s_setprio(1);
#pragma unroll
          for (int t4 = 0; t4 < 2; ++t4) {
            int kk = 32 * c + ((q16 >> 2) << 3) + (t4 << 2) + (q16 & 3);
            int fk = (kk & 7) ^ ((kk >> 1) & 4);
            const char* krow = ksb + kk * 128;
            int in0 = (g * 16) ^ (fk << 4);
            s16x8 kf0 = *(const s16x8*)(krow + in0);
            s16x8 kf1 = *(const s16x8*)(krow + (in0 ^ 64));
#pragma unroll
            for (int h = 0; h < 2; ++h) {
              f32x4 sv = {0.f, 0.f, 0.f, 0.f};
              sv = MFMA(kf0, qa[h][0], sv);
              sv = MFMA(kf1, qa[h][1], sv);
              sA[t4][h] = sv;
            }
          }
          __builtin_amdgcn_s_setprio(0);

          s16x8 wf = *(const s16x8*)((const char*)wl + (kb + 32 * c + 8 * g) * 2);

          union { s16x8 v; unsigned u[4]; } pb[2];
#pragma unroll
          for (int h = 0; h < 2; ++h) {
            int qc = qw0 + 16 * h + q16;
#pragma unroll
            for (int t4 = 0; t4 < 2; ++t4) {
              float a0 = ex2(sA[t4][h][0]), a1 = ex2(sA[t4][h][1]);
              float a2 = ex2(sA[t4][h][2]), a3 = ex2(sA[t4][h][3]);
              if (causal) {
                int k0 = kb + 32 * c + 8 * g + 4 * t4;
                a0 = (k0 + 0 <= qc) ? a0 : 0.f;
                a1 = (k0 + 1 <= qc) ? a1 : 0.f;
                a2 = (k0 + 2 <= qc) ? a2 : 0.f;
                a3 = (k0 + 3 <= qc) ? a3 : 0.f;
              }
              pb[h].u[t4 * 2 + 0] = cvtpk(a0, a1);
              pb[h].u[t4 * 2 + 1] = cvtpk(a2, a3);
            }
          }

          __builtin_amdgcn_s_setprio(1);
#pragma unroll
          for (int dt = 0; dt < 4; ++dt) {
            int d = dt * 16 + q16;
            int fv = (d & 7) ^ ((d >> 1) & 4);
            s16x8 vf = *(const s16x8*)(vsb + d * 128 + ((64 * c + 16 * g) ^ (fv << 4)));
#pragma unroll
            for (int h = 0; h < 2; ++h)
              o[h][dt] = MFMA(vf, pb[h].v, o[h][dt]);
          }
#pragma unroll
          for (int h = 0; h < 2; ++h)
            lw[h] = MFMA(wf, pb[h].v, lw[h]);
          __builtin_amdgcn_s_setprio(0);
        }
      }
    }

#pragma unroll
    for (int h = 0; h < 2; ++h) {
      float inv = rcp_(lw[h][0]);
      float* op = out + ((size_t)bh * 2048 + qw0 + 16 * h + q16) * 64 + g * 4;
#pragma unroll
      for (int dt = 0; dt < 4; ++dt)
        *(f32x4*)(op + dt * 16) = o[h][dt] * inv;
    }
  };

  run_phase(15 - p);   // heavy tile: 32-2p k-tiles
  run_phase(p);        // light tile: 2p+2 k-tiles (total 34, constant)
#undef STAGE_T
}

// ------------------------------------------------------------------- launcher
extern "C" void kernel_launch(void* const* d_in, const int* in_sizes, int n_in,
                              void* d_out, int out_size, void* d_ws, size_t ws_size,
                              hipStream_t stream) {
  const float* hs   = (const float*)d_in[0];
  const float* mask = (const float*)d_in[1];
  const float* Wq   = (const float*)d_in[2];
  const float* bq   = (const float*)d_in[3];
  const float* Wk   = (const float*)d_in[4];
  const float* bk   = (const float*)d_in[5];
  const float* Wv   = (const float*)d_in[6];
  const float* bv   = (const float*)d_in[7];
  float* out = (float*)d_out;

  char* w = (char*)d_ws;
  u16* Xb  = (u16*)w; w += (size_t)8192 * 1024 * 2;
  u16* Wqb = (u16*)w; w += (size_t)1024 * 1024 * 2;
  u16* Wkb = (u16*)w; w += (size_t)1024 * 1024 * 2;
  u16* Wvb = (u16*)w; w += (size_t)1024 * 1024 * 2;
  u16* Qw  = (u16*)w; w += (size_t)8192 * 1024 * 2;
  u16* Kw  = (u16*)w; w += (size_t)8192 * 1024 * 2;
  u16* Vtw = (u16*)w; w += (size_t)8192 * 1024 * 2;
  u16* Wm  = (u16*)w; w += (size_t)8192 * 2;

  cvt_all<<<5636, 256, 0, stream>>>(hs, Wq, Wk, Wv, mask, Xb, Wqb, Wkb, Wvb, Wm);
  qkv_gemm<<<768, 512, 0, stream>>>(Xb, Wqb, Wkb, Wvb, bq, bk, bv, Wm, Qw, Kw, Vtw);
  attn_fwd<<<512, 256, 0, stream>>>(Qw, Kw, Vtw, Wm, out);
}

// Round 15
// 129.371 us; speedup vs baseline: 1.0571x; 1.0072x over previous
//
#include <hip/hip_runtime.h>
#include <hip/hip_bf16.h>

// CausalSelfAttention: B=4 T=2048 H=1024 NH=16 HD=64, fp32 I/O, bf16 MFMA internal.
// cvt_all(X,W*)->bf16 + w=exp2(mask*log2e) ; fused QKV NT-GEMM v5: 256x128x32,
// 4 waves of 128x64 (8 A-frags x 4 B-frags: 25% less LDS bytes/FLOP than 64x64
// waves) + 2 blocks/CU (LDS 48KB dbuf) — combines R11's wave shape with R12's
// concurrency; 64B rows with swizzle f(row)=(row>>1)&3 (2-way = free);
// counted vmcnt(6); LDS-staged coalesced epilogue (V rows pre-scaled by w) ;
// flash attn: q-tile PAIR blocks, QBLK=128, quad-buffered K/V prefetch depth 2,
// ONE barrier per k-tile, vmcnt(8)/(4)/(0), swapped QK^T, no-max exp2 softmax,
// w-fragment denominator.

typedef float  f32x4 __attribute__((ext_vector_type(4)));
typedef short  s16x8 __attribute__((ext_vector_type(8)));
typedef unsigned short u16;

#define LOG2E 1.44269504088896340736f

__device__ __forceinline__ u16 f2bf(float f) {
  unsigned u = __float_as_uint(f);
  u += 0x7FFFu + ((u >> 16) & 1u);   // RNE (inputs finite)
  return (u16)(u >> 16);
}
__device__ __forceinline__ float bf2f(u16 v) {
  return __uint_as_float(((unsigned)v) << 16);
}
__device__ __forceinline__ float ex2(float x) {
#if __has_builtin(__builtin_amdgcn_exp2f)
  return __builtin_amdgcn_exp2f(x);
#else
  return exp2f(x);
#endif
}
__device__ __forceinline__ float rcp_(float x) {
#if __has_builtin(__builtin_amdgcn_rcpf)
  return __builtin_amdgcn_rcpf(x);
#else
  return 1.0f / x;
#endif
}
__device__ __forceinline__ unsigned cvtpk(float lo, float hi) {
  unsigned r;
  asm("v_cvt_pk_bf16_f32 %0, %1, %2" : "=v"(r) : "v"(lo), "v"(hi));
  return r;
}
__device__ __forceinline__ void bar() {
  asm volatile("" ::: "memory");
  __builtin_amdgcn_s_barrier();
  asm volatile("" ::: "memory");
}

#define GLOAD16(gp, lp)                                                          \
  __builtin_amdgcn_global_load_lds(                                              \
      (const __attribute__((address_space(1))) void*)(gp),                       \
      (__attribute__((address_space(3))) void*)(lp), 16, 0, 0)

#define MFMA(a, b, c) __builtin_amdgcn_mfma_f32_16x16x32_bf16((a), (b), (c), 0, 0, 0)

// ---------------------------- fp32 -> bf16 (X, Wq, Wk, Wv) + w = exp2(mask*log2e)
__global__ __launch_bounds__(256) void cvt_all(
    const float* __restrict__ hs, const float* __restrict__ wq,
    const float* __restrict__ wk, const float* __restrict__ wv,
    const float* __restrict__ maskp,
    u16* __restrict__ xo, u16* __restrict__ qo, u16* __restrict__ ko,
    u16* __restrict__ vo, u16* __restrict__ wm) {
  int b = blockIdx.x;
  const float* s;
  u16* d;
  size_t i;
  bool isw = false;
  if (b < 4096) { s = hs; d = xo; i = (size_t)b * 256 + threadIdx.x; }
  else if (b < 5632) {
    int w = (b - 4096) >> 9, r = (b - 4096) & 511;
    s = (w == 0) ? wq : (w == 1) ? wk : wv;
    d = (w == 0) ? qo : (w == 1) ? ko : vo;
    i = (size_t)r * 256 + threadIdx.x;
  } else {  // 4 blocks: w = exp2(mask * log2e), 8192 elems
    s = maskp; d = wm; i = (size_t)(b - 5632) * 256 + threadIdx.x;
    isw = true;
  }
  const float4* sp = (const float4*)s + i * 2;
  float4 a = sp[0], c = sp[1];
  s16x8 r8;
  if (isw) {
    r8[0] = f2bf(ex2(a.x * LOG2E)); r8[1] = f2bf(ex2(a.y * LOG2E));
    r8[2] = f2bf(ex2(a.z * LOG2E)); r8[3] = f2bf(ex2(a.w * LOG2E));
    r8[4] = f2bf(ex2(c.x * LOG2E)); r8[5] = f2bf(ex2(c.y * LOG2E));
    r8[6] = f2bf(ex2(c.z * LOG2E)); r8[7] = f2bf(ex2(c.w * LOG2E));
  } else {
    r8[0] = f2bf(a.x); r8[1] = f2bf(a.y); r8[2] = f2bf(a.z); r8[3] = f2bf(a.w);
    r8[4] = f2bf(c.x); r8[5] = f2bf(c.y); r8[6] = f2bf(c.z); r8[7] = f2bf(c.w);
  }
  *(s16x8*)(d + i * 8) = r8;
}

// ------------------------------------------------------------------- QKV GEMM
// 256x128 tile, BK=32, 4 waves (2m x 2n of 128x64; acc[8][4]=128 VGPR).
// LDS 48KB: A dbuf 2x16KB @0, B dbuf 2x8KB @32768 -> 2 blocks/CU (VGPR-capped).
// 64B rows; involution swizzle slot ^= (row>>1)&3 on staging SOURCE + frag reads
// (2-way bank aliasing = free; plain row&3 would be 4-way).
// Per K-tile: STAGE(next, 6 gloads); vmcnt(6); bar; 12 ds_read + 32 MFMA; bar.
__global__ __launch_bounds__(256, 2) void qkv_gemm(
    const u16* __restrict__ Xb,
    const u16* __restrict__ Wqb, const u16* __restrict__ Wkb,
    const u16* __restrict__ Wvb,
    const float* __restrict__ bq, const float* __restrict__ bk,
    const float* __restrict__ bv, const u16* __restrict__ Wm,
    u16* __restrict__ Qo, u16* __restrict__ Ko, u16* __restrict__ Vto) {
  int bid0 = blockIdx.x;
  int bid  = (bid0 & 7) * 96 + (bid0 >> 3);  // XCD swizzle, 768 = 8*96 bijective
  int which = bid % 3;                       // balanced Q/K/V mix per XCD
  int rt = bid / 3;
  int mt = rt >> 3, nt = rt & 7;             // 32 m-tiles x 8 n-tiles
  const u16* W = (which == 0) ? Wqb : (which == 1) ? Wkb : Wvb;
  const float* bias = (which == 0) ? bq : (which == 1) ? bk : bv;

  __shared__ __align__(16) char lds[49152];

  int tid = threadIdx.x;
  int lane = tid & 63, wid = tid >> 6;
  int q16 = lane & 15, g = lane >> 4;
  int wr = wid >> 1, wc = wid & 1;           // 2M x 2N waves (each 128x64)

  // staging source (pre-swizzled): thread covers (row = 64c + srow, slot tid&3)
  int srow = tid >> 2;
  int sw = (((tid & 3) ^ ((srow >> 1) & 3)) << 4);  // f(row)=(row>>1)&3; +64 rows preserves it
  const char* Asrc = (const char*)Xb + (size_t)(mt * 256 + srow) * 2048 + sw;
  const char* Bsrc = (const char*)W  + (size_t)(nt * 128 + srow) * 2048 + sw;

  // fragment read slot: frag rows are 16-aligned + q16 -> f(row) = (q16>>1)&3
  int slotA = (g ^ ((q16 >> 1) & 3)) << 4;

#define STAGE_AB(tt, buf) do { size_t so = (size_t)(tt) * 64;                    \
    GLOAD16(Asrc + so,          lds + (buf) * 16384 + tid * 16);                 \
    GLOAD16(Asrc + so + 131072, lds + (buf) * 16384 + 4096 + tid * 16);          \
    GLOAD16(Asrc + so + 262144, lds + (buf) * 16384 + 8192 + tid * 16);          \
    GLOAD16(Asrc + so + 393216, lds + (buf) * 16384 + 12288 + tid * 16);         \
    GLOAD16(Bsrc + so,          lds + 32768 + (buf) * 8192 + tid * 16);          \
    GLOAD16(Bsrc + so + 131072, lds + 32768 + (buf) * 8192 + 4096 + tid * 16); } while (0)

  STAGE_AB(0, 0);

  f32x4 acc[8][4] = {};
  s16x8 fA[8], fB[4];

#pragma unroll 1
  for (int i = 0; i < 32; ++i) {
    int buf = i & 1;
    if (i < 31) {
      STAGE_AB(i + 1, buf ^ 1);
      asm volatile("s_waitcnt vmcnt(6)" ::: "memory");  // tile i's 6 loads done
    } else {
      asm volatile("s_waitcnt vmcnt(0)" ::: "memory");
    }
    bar();
    const char* pa = lds + buf * 16384 + (wr * 128 + q16) * 64 + slotA;
    const char* pb = lds + 32768 + buf * 8192 + (wc * 64 + q16) * 64 + slotA;
#pragma unroll
    for (int m = 0; m < 8; ++m) fA[m] = *(const s16x8*)(pa + m * 1024);
#pragma unroll
    for (int n = 0; n < 4; ++n) fB[n] = *(const s16x8*)(pb + n * 1024);
    __builtin_amdgcn_s_setprio(1);
#pragma unroll
    for (int m = 0; m < 8; ++m)
#pragma unroll
      for (int n = 0; n < 4; ++n)
        acc[m][n] = MFMA(fA[m], fB[n], acc[m][n]);
    __builtin_amdgcn_s_setprio(0);
    bar();  // all reads of buf done before iter i+1 STAGEs into it
  }
#undef STAGE_AB

  // ---- epilogue: per-wave 12KB LDS region, 2 static passes of 64 rows ----
  float qsc = (which == 0) ? (0.125f * LOG2E) : 1.0f;
  u16* Out = (which == 0) ? Qo : (which == 1) ? Ko : Vto;
  int h0 = nt * 2 + wc;                       // wave's head
  u16* tile = (u16*)(void*)(lds + wid * 12288);  // [64][72] u16
  const char* tb = (const char*)tile;
  int rl = lane >> 3, cb = (lane & 7) * 16;

#define EPIPASS(P) do {                                                          \
    int mbase = mt * 256 + wr * 128 + (P) * 64;                                  \
    int bb = mbase >> 11, t0 = mbase & 2047;                                     \
    if (which != 2) {                                                            \
      _Pragma("unroll")                                                          \
      for (int n = 0; n < 4; ++n) {                                              \
        float bvl = bias[h0 * 64 + n * 16 + q16];                                \
        _Pragma("unroll")                                                        \
        for (int mm = 0; mm < 4; ++mm)                                           \
          _Pragma("unroll")                                                      \
          for (int j = 0; j < 4; ++j)                                            \
            tile[(mm * 16 + g * 4 + j) * 72 + n * 16 + q16] =                    \
                f2bf((acc[(P) * 4 + mm][n][j] + bvl) * qsc);                     \
      }                                                                          \
    } else {                                                                     \
      const u16* wrow = Wm + (size_t)bb * 2048 + t0;                             \
      float wv[4][4];                                                            \
      _Pragma("unroll")                                                          \
      for (int mm = 0; mm < 4; ++mm)                                             \
        _Pragma("unroll")                                                        \
        for (int j = 0; j < 4; ++j)                                              \
          wv[mm][j] = bf2f(wrow[mm * 16 + g * 4 + j]);                           \
      _Pragma("unroll")                                                          \
      for (int n = 0; n < 4; ++n) {                                              \
        float bvl = bias[h0 * 64 + n * 16 + q16];                                \
        _Pragma("unroll")                                                        \
        for (int mm = 0; mm < 4; ++mm)                                           \
          _Pragma("unroll")                                                      \
          for (int j = 0; j < 4; ++j)                                            \
            tile[(n * 16 + q16) * 72 + mm * 16 + g * 4 + j] =                    \
                f2bf((acc[(P) * 4 + mm][n][j] + bvl) * wv[mm][j]);               \
      }                                                                          \
    }                                                                            \
    asm volatile("" ::: "memory");                                               \
    if (which != 2) {                                                            \
      char* gbase = (char*)(Out + ((size_t)(bb * 16 + h0) * 2048 + t0) * 64);    \
      _Pragma("unroll")                                                          \
      for (int c = 0; c < 8; ++c) {                                              \
        int row = rl + c * 8;                                                    \
        s16x8 v = *(const s16x8*)(tb + row * 144 + cb);                          \
        *(s16x8*)(gbase + row * 128 + cb) = v;                                   \
      }                                                                          \
    } else {                                                                     \
      char* gbase = (char*)Out + ((size_t)(bb * 16 + h0) * 64) * 4096 + t0 * 2;  \
      _Pragma("unroll")                                                          \
      for (int c = 0; c < 8; ++c) {                                              \
        int d = rl + c * 8;                                                      \
        s16x8 v = *(const s16x8*)(tb + d * 144 + cb);                            \
        *(s16x8*)(gbase + (size_t)d * 4096 + cb) = v;                            \
      }                                                                          \
    }                                                                            \
    asm volatile("" ::: "memory"); } while (0)

  EPIPASS(0);
  EPIPASS(1);
#undef EPIPASS
}

// ------------------------------------------------------------- flash attention
// grid 512 = 64 bh x 8 pair-blocks (q-tiles 15-p then p -> 34 k-tiles each).
// 4 waves x 32 q-rows. QUAD-buffered K/V, prefetch depth 2 (safe write-to-read
// distance under 1-barrier-per-tile sync), counted vmcnt(8)/(4)/(0).
__global__ __launch_bounds__(256, 2) void attn_fwd(
    const u16* __restrict__ Qw, const u16* __restrict__ Kw,
    const u16* __restrict__ Vtw, const u16* __restrict__ Wm,
    float* __restrict__ out) {
  int bid0 = blockIdx.x;
  int bid = (bid0 & 7) * 64 + (bid0 >> 3);  // XCD swizzle: 8 bh per XCD
  int bh = bid >> 3, p = bid & 7;
  int tid = threadIdx.x;
  int lane = tid & 63, wid = tid >> 6;
  int q16 = lane & 15, g = lane >> 4;

  __shared__ __align__(16) char Ks[4][8192];   // [k 64][128B] swizzled
  __shared__ __align__(16) char Vs[4][8192];   // V^T [d 64][128B k] swizzled
  __shared__ __align__(16) u16 wl[2048];       // w row (bf16)

  int srow = tid >> 3;
  int sinner = (tid & 7) << 4;
  int fs = (srow & 7) ^ ((srow >> 1) & 4);
  int ssw = sinner ^ (fs << 4);
  const char* Kg = (const char*)Kw + ((size_t)bh * 2048 + srow) * 128 + ssw;
  const char* Vg = (const char*)Vtw + ((size_t)bh * 64 + srow) * 4096 + ssw;

#define STAGE_T(kt, b) do {                                                      \
    GLOAD16(Kg + (size_t)(kt) * 8192,        Ks[b] + tid * 16);                  \
    GLOAD16(Kg + (size_t)(kt) * 8192 + 4096, Ks[b] + tid * 16 + 4096);           \
    GLOAD16(Vg + (size_t)(kt) * 128,          Vs[b] + tid * 16);                 \
    GLOAD16(Vg + (size_t)(kt) * 128 + 131072, Vs[b] + tid * 16 + 4096); } while (0)

  // wl staged once (drains as oldest entry at the first counted vmcnt)
  GLOAD16((const char*)Wm + (size_t)(bh >> 4) * 4096 + tid * 16,
          (char*)wl + tid * 16);

  auto run_phase = [&](int qtl) {
    int nt = 2 * qtl + 2;
    int qw0 = (qtl << 7) + wid * 32;
    size_t qr = (size_t)bh * 2048 + qw0 + q16;
    s16x8 qa[2][2];
#pragma unroll
    for (int h = 0; h < 2; ++h) {
      qa[h][0] = *(const s16x8*)(Qw + (qr + 16 * h) * 64 + g * 8);
      qa[h][1] = *(const s16x8*)(Qw + (qr + 16 * h) * 64 + 32 + g * 8);
    }
    bar();              // previous phase's readers done before re-staging bufs
    STAGE_T(0, 0);
    STAGE_T(1, 1);

    f32x4 o[2][4] = {};
    f32x4 lw[2] = {};

#pragma unroll 1
    for (int kt = 0; kt < nt; ++kt) {
      if (kt + 2 < nt) {
        STAGE_T(kt + 2, (kt + 2) & 3);
        asm volatile("s_waitcnt vmcnt(8)" ::: "memory");  // tile kt landed
      } else if (kt + 1 < nt) {
        asm volatile("s_waitcnt vmcnt(4)" ::: "memory");
      } else {
        asm volatile("s_waitcnt vmcnt(0)" ::: "memory");
      }
      bar();            // the ONLY barrier per k-tile

      if (64 * kt <= qw0 + 31) {
        int kb = kt << 6;
        const char* ksb = Ks[kt & 3];
        const char* vsb = Vs[kt & 3];
        bool causal = (64 * kt + 63 > qw0);
#pragma unroll
        for (int c = 0; c < 2; ++c) {
          f32x4 sA[2][2];
          __builtin_amdgcn_s_setprio(1);
#pragma unroll
          for (int t4 = 0; t4 < 2; ++t4) {
            int kk = 32 * c + ((q16 >> 2) << 3) + (t4 << 2) + (q16 & 3);
            int fk = (kk & 7) ^ ((kk >> 1) & 4);
            const char* krow = ksb + kk * 128;
            int in0 = (g * 16) ^ (fk << 4);
            s16x8 kf0 = *(const s16x8*)(krow + in0);
            s16x8 kf1 = *(const s16x8*)(krow + (in0 ^ 64));
#pragma unroll
            for (int h = 0; h < 2; ++h) {
              f32x4 sv = {0.f, 0.f, 0.f, 0.f};
              sv = MFMA(kf0, qa[h][0], sv);
              sv = MFMA(kf1, qa[h][1], sv);
              sA[t4][h] = sv;
            }
          }
          __builtin_amdgcn_s_setprio(0);

          s16x8 wf = *(const s16x8*)((const char*)wl + (kb + 32 * c + 8 * g) * 2);

          union { s16x8 v; unsigned u[4]; } pb[2];
#pragma unroll
          for (int h = 0; h < 2; ++h) {
            int qc = qw0 + 16 * h + q16;
#pragma unroll
            for (int t4 = 0; t4 < 2; ++t4) {
              float a0 = ex2(sA[t4][h][0]), a1 = ex2(sA[t4][h][1]);
              float a2 = ex2(sA[t4][h][2]), a3 = ex2(sA[t4][h][3]);
              if (causal) {
                int k0 = kb + 32 * c + 8 * g + 4 * t4;
                a0 = (k0 + 0 <= qc) ? a0 : 0.f;
                a1 = (k0 + 1 <= qc) ? a1 : 0.f;
                a2 = (k0 + 2 <= qc) ? a2 : 0.f;
                a3 = (k0 + 3 <= qc) ? a3 : 0.f;
              }
              pb[h].u[t4 * 2 + 0] = cvtpk(a0, a1);
              pb[h].u[t4 * 2 + 1] = cvtpk(a2, a3);
            }
          }

          __builtin_amdgcn_s_setprio(1);
#pragma unroll
          for (int dt = 0; dt < 4; ++dt) {
            int d = dt * 16 + q16;
            int fv = (d & 7) ^ ((d >> 1) & 4);
            s16x8 vf = *(const s16x8*)(vsb + d * 128 + ((64 * c + 16 * g) ^ (fv << 4)));
#pragma unroll
            for (int h = 0; h < 2; ++h)
              o[h][dt] = MFMA(vf, pb[h].v, o[h][dt]);
          }
#pragma unroll
          for (int h = 0; h < 2; ++h)
            lw[h] = MFMA(wf, pb[h].v, lw[h]);
          __builtin_amdgcn_s_setprio(0);
        }
      }
    }

#pragma unroll
    for (int h = 0; h < 2; ++h) {
      float inv = rcp_(lw[h][0]);
      float* op = out + ((size_t)bh * 2048 + qw0 + 16 * h + q16) * 64 + g * 4;
#pragma unroll
      for (int dt = 0; dt < 4; ++dt)
        *(f32x4*)(op + dt * 16) = o[h][dt] * inv;
    }
  };

  run_phase(15 - p);   // heavy tile: 32-2p k-tiles
  run_phase(p);        // light tile: 2p+2 k-tiles (total 34, constant)
#undef STAGE_T
}

// ------------------------------------------------------------------- launcher
extern "C" void kernel_launch(void* const* d_in, const int* in_sizes, int n_in,
                              void* d_out, int out_size, void* d_ws, size_t ws_size,
                              hipStream_t stream) {
  const float* hs   = (const float*)d_in[0];
  const float* mask = (const float*)d_in[1];
  const float* Wq   = (const float*)d_in[2];
  const float* bq   = (const float*)d_in[3];
  const float* Wk   = (const float*)d_in[4];
  const float* bk   = (const float*)d_in[5];
  const float* Wv   = (const float*)d_in[6];
  const float* bv   = (const float*)d_in[7];
  float* out = (float*)d_out;

  char* w = (char*)d_ws;
  u16* Xb  = (u16*)w; w += (size_t)8192 * 1024 * 2;
  u16* Wqb = (u16*)w; w += (size_t)1024 * 1024 * 2;
  u16* Wkb = (u16*)w; w += (size_t)1024 * 1024 * 2;
  u16* Wvb = (u16*)w; w += (size_t)1024 * 1024 * 2;
  u16* Qw  = (u16*)w; w += (size_t)8192 * 1024 * 2;
  u16* Kw  = (u16*)w; w += (size_t)8192 * 1024 * 2;
  u16* Vtw = (u16*)w; w += (size_t)8192 * 1024 * 2;
  u16* Wm  = (u16*)w; w += (size_t)8192 * 2;

  cvt_all<<<5636, 256, 0, stream>>>(hs, Wq, Wk, Wv, mask, Xb, Wqb, Wkb, Wvb, Wm);
  qkv_gemm<<<768, 256, 0, stream>>>(Xb, Wqb, Wkb, Wvb, bq, bk, bv, Wm, Qw, Kw, Vtw);
  attn_fwd<<<512, 256, 0, stream>>>(Qw, Kw, Vtw, Wm, out);
}